// Round 1
// 316.974 us; speedup vs baseline: 1.0303x; 1.0303x over previous
//
#include <hip/hip_runtime.h>

#define DIM 2048
#define NH 16
#define HD 128
#define BB 2
#define LL 2048
#define MROWS (BB * LL)   // 4096
#define NKV 2304          // 2048 q + 128 k + 128 v
#define NT 32             // K=2048 / BK=64 for both big GEMMs

typedef __attribute__((ext_vector_type(8))) short short8;
typedef __attribute__((ext_vector_type(4))) float floatx4;

__device__ inline ushort f2bf(float f) {
    union { float f; unsigned u; } v; v.f = f;
    unsigned r = v.u + 0x7FFFu + ((v.u >> 16) & 1u);
    return (ushort)(r >> 16);
}

#define GL16(g, l)                                                         \
    __builtin_amdgcn_global_load_lds(                                      \
        (const __attribute__((address_space(1))) unsigned int*)(g),        \
        (__attribute__((address_space(3))) unsigned int*)(l), 16, 0, 0)

__device__ __forceinline__ short8 ld8(const ushort* p) {
    return *reinterpret_cast<const short8*>(p);
}

// ---------------------------------------------------------------------------
// elementwise f32 -> bf16 (8 elems/thread)
// ---------------------------------------------------------------------------
__global__ __launch_bounds__(256) void conv_bf16(const float* __restrict__ in,
                                                 ushort* __restrict__ out) {
    size_t i = ((size_t)blockIdx.x * 256 + threadIdx.x) * 8;
    float4 a = *reinterpret_cast<const float4*>(in + i);
    float4 b = *reinterpret_cast<const float4*>(in + i + 4);
    ushort o[8] = {f2bf(a.x), f2bf(a.y), f2bf(a.z), f2bf(a.w),
                   f2bf(b.x), f2bf(b.y), f2bf(b.z), f2bf(b.w)};
    *reinterpret_cast<uint4*>(out + i) = *reinterpret_cast<uint4*>(o);
}

// ---------------------------------------------------------------------------
// merged weight prep: transpose+convert Wq,Wo,Wk,Wv in one launch.
// ---------------------------------------------------------------------------
__global__ __launch_bounds__(256) void wprep(const float* __restrict__ Wq,
                                             const float* __restrict__ Wk,
                                             const float* __restrict__ Wv,
                                             const float* __restrict__ Wo,
                                             ushort* __restrict__ Wcatt,
                                             ushort* __restrict__ Wot) {
    __shared__ ushort T[64][72];
    const int bid = blockIdx.x;
    const float* in;
    ushort* out;
    int in_ld, c0, r0;
    const int out_ld = 2048;
    if (bid < 1024) {
        in = Wq; out = Wcatt; in_ld = 2048;
        c0 = (bid & 31) * 64; r0 = (bid >> 5) * 64;
    } else if (bid < 2048) {
        int t = bid - 1024;
        in = Wo; out = Wot; in_ld = 2048;
        c0 = (t & 31) * 64; r0 = (t >> 5) * 64;
    } else if (bid < 2112) {
        int t = bid - 2048;
        in = Wk; out = Wcatt + (size_t)2048 * 2048; in_ld = 128;
        c0 = (t & 1) * 64; r0 = (t >> 1) * 64;
    } else {
        int t = bid - 2112;
        in = Wv; out = Wcatt + (size_t)2176 * 2048; in_ld = 128;
        c0 = (t & 1) * 64; r0 = (t >> 1) * 64;
    }
    const int tid = threadIdx.x;
#pragma unroll
    for (int rep = 0; rep < 4; ++rep) {
        int idx = tid + rep * 256;
        int r = idx >> 4, c4 = idx & 15;
        float4 f = *reinterpret_cast<const float4*>(
            in + (size_t)(r0 + r) * in_ld + c0 + c4 * 4);
        T[r][c4 * 4 + 0] = f2bf(f.x);
        T[r][c4 * 4 + 1] = f2bf(f.y);
        T[r][c4 * 4 + 2] = f2bf(f.z);
        T[r][c4 * 4 + 3] = f2bf(f.w);
    }
    __syncthreads();
#pragma unroll
    for (int rep = 0; rep < 4; ++rep) {
        int idx = tid + rep * 256;
        int cr = idx >> 4, rc4 = idx & 15;
        uint a0 = (uint)T[rc4 * 4 + 0][cr] | ((uint)T[rc4 * 4 + 1][cr] << 16);
        uint a1 = (uint)T[rc4 * 4 + 2][cr] | ((uint)T[rc4 * 4 + 3][cr] << 16);
        uint2 val = {a0, a1};
        *reinterpret_cast<uint2*>(
            out + (size_t)(c0 + cr) * out_ld + r0 + rc4 * 4) = val;
    }
}

// ---------------------------------------------------------------------------
// 256x256 8-phase bf16 GEMM (T3+T4 counted vmcnt, T5 setprio), K=2048 fixed.
// Y = A @ Bt^T, A: Mx2048, Bt: Nx2048 (both bf16 row-major), Y f32 MxN.
// 512 threads = 8 waves (2M x 4N), per-wave 128x64 output, BK=64.
// LDS 128 KiB: 2 dbuf x 4 units(16KB): [B-lo, B-hi, A-lo, A-hi].
// Per K-tile 4 phases; each phase: ds_read subtile + 1 half-tile GL16 stage
//  -> s_barrier -> lgkmcnt(0) -> setprio(1) -> 16 MFMA -> setprio(0) -> bar.
// vmcnt(6) once per K-tile (3 half-tiles in flight across barriers).
// Unit issue order satisfies read-before-overwrite for 2-deep buffering:
//   phi0 issues unit3(t+1); phi1..3 issue unit0..2(t+2); B fully read in phi0,
//   A-lo last read phi2 (< phi3 issue), A-hi last read phi2 (< next phi0).
// XOR chunk swizzle (chunk ^ (row&7)): linear GL16 dest, pre-swizzled global
// source, ^sel on read -> 0 bank conflicts (same scheme as previous kernel).
// ---------------------------------------------------------------------------
template <int U>
__device__ __forceinline__ void stage_unit(const ushort* __restrict__ A,
                                           const ushort* __restrict__ Bt,
                                           ushort* lbase, uint offA, uint offB,
                                           int t) {
    if (t >= NT) return;
    const ushort* g = (U < 2) ? Bt : A;
    uint off = ((U < 2) ? offB : offA) + ((U & 1) ? 128u * 2048u : 0u) +
               (uint)t * 64u;
    ushort* l = lbase + U * 8192;
    GL16(g + off, l + (size_t)threadIdx.x * 8);
    GL16(g + off + 64u * 2048u, l + (size_t)(threadIdx.x + 512) * 8);
}

__global__ __launch_bounds__(512, 2) void gemm8p(const ushort* __restrict__ A,
                                                 const ushort* __restrict__ Bt,
                                                 float* __restrict__ Y,
                                                 int N) {
    __shared__ __attribute__((aligned(16))) ushort lds[65536];  // 128 KiB
    const int tid = threadIdx.x;
    const int lane = tid & 63;
    const int w = tid >> 6;
    const int wm = w >> 2, wn = w & 3;
    const int col = lane & 15, quad = lane >> 4;
    const int sel = col & 7;
    const int m0 = blockIdx.y * 256, n0 = blockIdx.x * 256;

    // staging: slot s=tid and s=tid+512; row r=s>>3, swizzled chunk=(s&7)^(r&7)
    const int r0 = tid >> 3;
    const int gc0 = (tid & 7) ^ (r0 & 7);
    const uint offA = (uint)(m0 + r0) * 2048u + (uint)gc0 * 8u;
    const uint offB = (uint)(n0 + r0) * 2048u + (uint)gc0 * 8u;

    floatx4 acc[8][4];
#pragma unroll
    for (int mt = 0; mt < 8; ++mt)
#pragma unroll
        for (int nt = 0; nt < 4; ++nt) acc[mt][nt] = (floatx4){0.f, 0.f, 0.f, 0.f};

    // LDS read bases (ushort idx within one dbuf half = 32768):
    const int aoff0 = (2 + wm) * 8192 + col * 64;
    const int boff0 = (wn >> 1) * 8192 + ((wn & 1) * 64 + col) * 64;
    const int koff0 = (quad ^ sel) * 8;        // ks=0 chunk
    const int koff1 = ((4 + quad) ^ sel) * 8;  // ks=1 chunk

    // prologue: stage tile0 (4 units) + tile1 units 0..2 -> 7 half-tiles
    stage_unit<0>(A, Bt, lds, offA, offB, 0);
    stage_unit<1>(A, Bt, lds, offA, offB, 0);
    stage_unit<2>(A, Bt, lds, offA, offB, 0);
    stage_unit<3>(A, Bt, lds, offA, offB, 0);
    stage_unit<0>(A, Bt, lds + 32768, offA, offB, 1);
    stage_unit<1>(A, Bt, lds + 32768, offA, offB, 1);
    stage_unit<2>(A, Bt, lds + 32768, offA, offB, 1);
    asm volatile("s_waitcnt vmcnt(6)" ::: "memory");  // tile0 complete
    __builtin_amdgcn_s_barrier();

#pragma unroll 2
    for (int t = 0; t < NT; ++t) {
        ushort* lb = lds + (t & 1) * 32768;
        ushort* lbn = lds + ((t + 1) & 1) * 32768;

        // ---- phi0: 12 ds_reads (A mt0-3 ks0, B all-nt both-ks) ----
        short8 a0[4], b0[4], b1[4];
#pragma unroll
        for (int mt = 0; mt < 4; ++mt)
            a0[mt] = ld8(lb + aoff0 + mt * 16 * 64 + koff0);
#pragma unroll
        for (int nt = 0; nt < 4; ++nt)
            b0[nt] = ld8(lb + boff0 + nt * 16 * 64 + koff0);
#pragma unroll
        for (int nt = 0; nt < 4; ++nt)
            b1[nt] = ld8(lb + boff0 + nt * 16 * 64 + koff1);
        stage_unit<3>(A, Bt, lbn, offA, offB, t + 1);  // A-hi of tile t+1
        __builtin_amdgcn_s_barrier();
        asm volatile("s_waitcnt lgkmcnt(0)" ::: "memory");
        __builtin_amdgcn_sched_barrier(0);
        __builtin_amdgcn_s_setprio(1);
#pragma unroll
        for (int mt = 0; mt < 4; ++mt)
#pragma unroll
            for (int nt = 0; nt < 4; ++nt)
                acc[mt][nt] = __builtin_amdgcn_mfma_f32_16x16x32_bf16(
                    a0[mt], b0[nt], acc[mt][nt], 0, 0, 0);
        __builtin_amdgcn_s_setprio(0);
        __builtin_amdgcn_s_barrier();

        // ---- phi1: 4 ds_reads (A mt4-7 ks0) ----
        short8 a1[4];
#pragma unroll
        for (int mt = 0; mt < 4; ++mt)
            a1[mt] = ld8(lb + aoff0 + (4 + mt) * 16 * 64 + koff0);
        stage_unit<0>(A, Bt, lb, offA, offB, t + 2);  // B-lo (read done phi0)
        __builtin_amdgcn_s_barrier();
        asm volatile("s_waitcnt lgkmcnt(0)" ::: "memory");
        __builtin_amdgcn_sched_barrier(0);
        __builtin_amdgcn_s_setprio(1);
#pragma unroll
        for (int mt = 0; mt < 4; ++mt)
#pragma unroll
            for (int nt = 0; nt < 4; ++nt)
                acc[4 + mt][nt] = __builtin_amdgcn_mfma_f32_16x16x32_bf16(
                    a1[mt], b0[nt], acc[4 + mt][nt], 0, 0, 0);
        __builtin_amdgcn_s_setprio(0);
        __builtin_amdgcn_s_barrier();

        // ---- phi2: 8 ds_reads (A mt0-7 ks1) ----
        short8 a2[4], a3[4];
#pragma unroll
        for (int mt = 0; mt < 4; ++mt)
            a2[mt] = ld8(lb + aoff0 + mt * 16 * 64 + koff1);
#pragma unroll
        for (int mt = 0; mt < 4; ++mt)
            a3[mt] = ld8(lb + aoff0 + (4 + mt) * 16 * 64 + koff1);
        stage_unit<1>(A, Bt, lb, offA, offB, t + 2);  // B-hi (read done phi0)
        __builtin_amdgcn_s_barrier();
        asm volatile("s_waitcnt lgkmcnt(0)" ::: "memory");
        __builtin_amdgcn_sched_barrier(0);
        __builtin_amdgcn_s_setprio(1);
#pragma unroll
        for (int mt = 0; mt < 4; ++mt)
#pragma unroll
            for (int nt = 0; nt < 4; ++nt)
                acc[mt][nt] = __builtin_amdgcn_mfma_f32_16x16x32_bf16(
                    a2[mt], b1[nt], acc[mt][nt], 0, 0, 0);
        __builtin_amdgcn_s_setprio(0);
        __builtin_amdgcn_s_barrier();

        // ---- phi3: 0 ds_reads; K-tile boundary vmcnt ----
        stage_unit<2>(A, Bt, lb, offA, offB, t + 2);  // A-lo (read done phi2)
        if (t < NT - 2)
            asm volatile("s_waitcnt vmcnt(6)" ::: "memory");  // tile t+1 ready
        else
            asm volatile("s_waitcnt vmcnt(0)" ::: "memory");  // drain tail
        __builtin_amdgcn_s_barrier();
        __builtin_amdgcn_s_setprio(1);
#pragma unroll
        for (int mt = 0; mt < 4; ++mt)
#pragma unroll
            for (int nt = 0; nt < 4; ++nt)
                acc[4 + mt][nt] = __builtin_amdgcn_mfma_f32_16x16x32_bf16(
                    a3[mt], b1[nt], acc[4 + mt][nt], 0, 0, 0);
        __builtin_amdgcn_s_setprio(0);
        __builtin_amdgcn_s_barrier();
    }

    // epilogue: C write (m89 C/D mapping: col=lane&15, row=quad*4+reg)
#pragma unroll
    for (int mt = 0; mt < 8; ++mt)
#pragma unroll
        for (int nt = 0; nt < 4; ++nt)
#pragma unroll
            for (int rr = 0; rr < 4; ++rr)
                Y[(size_t)(m0 + wm * 128 + mt * 16 + quad * 4 + rr) * N + n0 +
                  wn * 64 + nt * 16 + col] = acc[mt][nt][rr];
}

// ---------------------------------------------------------------------------
// RoPE + RMSNorm: fp32 in (token stride in_ld, head stride HD) -> bf16 out.
// ---------------------------------------------------------------------------
__global__ __launch_bounds__(256) void rope_rms_bf16(const float* __restrict__ in,
                                                     ushort* __restrict__ outb,
                                                     const float* __restrict__ cosb,
                                                     const float* __restrict__ sinb,
                                                     int heads, int nrows,
                                                     int in_ld) {
    int row = blockIdx.x * 4 + (threadIdx.x >> 6);
    int lane = threadIdx.x & 63;
    if (row >= nrows) return;
    int token = row / heads, head = row % heads;
    int l = token & (LL - 1);
    const float* p = in + (size_t)token * in_ld + head * HD;
    float x1 = p[lane];
    float x2 = p[lane + 64];
    float c = cosb[l * 64 + lane];
    float s = sinb[l * 64 + lane];
    float o1 = x1 * c + x2 * s;
    float o2 = -x1 * s + x2 * c;
    float ss = o1 * o1 + o2 * o2;
#pragma unroll
    for (int off = 32; off > 0; off >>= 1) ss += __shfl_xor(ss, off);
    float r = rsqrtf(ss * (1.0f / 128.0f) + 1e-6f);
    outb[(size_t)row * HD + lane] = f2bf(o1 * r);
    outb[(size_t)row * HD + lane + 64] = f2bf(o2 * r);
}

// ---------------------------------------------------------------------------
// V transpose + bf16: in f32 (B*L, in_ld) cols 0..127 -> vt (B,128,L) bf16.
// ---------------------------------------------------------------------------
__global__ __launch_bounds__(256) void vtrans(const float* __restrict__ v,
                                              ushort* __restrict__ vt,
                                              int in_ld) {
    __shared__ ushort T[64][72];
    const int l0 = blockIdx.x * 64, d0 = blockIdx.y * 64, b = blockIdx.z;
    const int tid = threadIdx.x;
#pragma unroll
    for (int rep = 0; rep < 4; ++rep) {
        int idx = tid + rep * 256;
        int r = idx >> 4, c4 = idx & 15;
        float4 f = *reinterpret_cast<const float4*>(
            v + (size_t)(b * LL + l0 + r) * in_ld + d0 + c4 * 4);
        T[r][c4 * 4 + 0] = f2bf(f.x);
        T[r][c4 * 4 + 1] = f2bf(f.y);
        T[r][c4 * 4 + 2] = f2bf(f.z);
        T[r][c4 * 4 + 3] = f2bf(f.w);
    }
    __syncthreads();
#pragma unroll
    for (int rep = 0; rep < 4; ++rep) {
        int idx = tid + rep * 256;
        int dr = idx >> 4, lc4 = idx & 15;
        uint a0 = (uint)T[lc4 * 4 + 0][dr] | ((uint)T[lc4 * 4 + 1][dr] << 16);
        uint a1 = (uint)T[lc4 * 4 + 2][dr] | ((uint)T[lc4 * 4 + 3][dr] << 16);
        uint2 val = {a0, a1};
        *reinterpret_cast<uint2*>(
            vt + (size_t)(b * HD + d0 + dr) * LL + l0 + lc4 * 4) = val;
    }
}

// ---------------------------------------------------------------------------
// Flash-style causal MQA attention, bf16 MFMA 16x16x32, load-balanced pairs.
// FIXED-MAX softmax: RMS-normed q,k bound scaled scores by sqrt(128)=11.31
// (Cauchy-Schwarz; bf16 rounding < +0.5%) -> constant max M=11.5, no running
// max / alpha / O-rescale. K/V tiles staged via GL16 with XOR chunk swizzle.
// ---------------------------------------------------------------------------
__global__ __launch_bounds__(256) void flash_mfma(const ushort* __restrict__ qb,
                                                  const ushort* __restrict__ kb,
                                                  const ushort* __restrict__ vt,
                                                  ushort* __restrict__ aob) {
    __shared__ ushort Ks[64 * 128];    // 16 KB, swizzled 16B chunks
    __shared__ ushort VTs[128 * 64];   // 16 KB, swizzled 16B chunks
    __shared__ ushort Ps[4][16][72];   // 9 KB, per-wave P buffer

    const int tid = threadIdx.x;
    const int w = tid >> 6, lane = tid & 63;
    const int col = lane & 15, quad = lane >> 4;
    const int pairIdx = blockIdx.x, bh = blockIdx.y;
    const int b = bh >> 4, h = bh & 15;
    const int sel = col & 7;  // read-side unswizzle (tile rows == col mod 8)
    // p = exp2(s*scl2 - M2), M2 = 11.5*log2e
    const float scl2 = 0.08838834764831845f * 1.44269504088896340736f;
    const float M2 = 11.5f * 1.44269504088896340736f;

    // K staging: slot s (16B) -> row=s>>4, glob chunk=(s&15)^(row&7)
    const int ksr[4] = {(tid + 0) >> 4, (tid + 256) >> 4, (tid + 512) >> 4,
                        (tid + 768) >> 4};
    // V staging: slot s -> row=s>>3, glob chunk=(s&7)^(row&7)
    const int vsr[4] = {(tid + 0) >> 3, (tid + 256) >> 3, (tid + 512) >> 3,
                        (tid + 768) >> 3};

    for (int sp = 0; sp < 2; ++sp) {
        const int qt = sp ? (31 - pairIdx) : pairIdx;
        const int q0 = qt * 64;

        const ushort* qrow =
            qb + ((size_t)(b * LL + q0 + w * 16 + col) * NH + h) * HD;
        short8 aq[4];
#pragma unroll
        for (int kc = 0; kc < 4; ++kc)
            aq[kc] = *reinterpret_cast<const short8*>(qrow + kc * 32 + quad * 8);

        float lrow[4] = {0.f, 0.f, 0.f, 0.f};
        floatx4 oacc[8];
#pragma unroll
        for (int dt = 0; dt < 8; ++dt) oacc[dt] = (floatx4){0.f, 0.f, 0.f, 0.f};

        const int ntiles = qt + 1;
        for (int kt = 0; kt < ntiles; ++kt) {
            const int k0 = kt * 64;
            __syncthreads();
            // ---- stage K tile 64x128 via GL16 (swizzled) ----
#pragma unroll
            for (int rep = 0; rep < 4; ++rep) {
                int slot = tid + rep * 256;
                int r = ksr[rep];
                int gc = (slot & 15) ^ (r & 7);
                GL16(kb + (size_t)(b * LL + k0 + r) * HD + gc * 8,
                     Ks + (size_t)slot * 8);
            }
            // ---- stage V^T tile 128x64 via GL16 (swizzled) ----
#pragma unroll
            for (int rep = 0; rep < 4; ++rep) {
                int slot = tid + rep * 256;
                int r = vsr[rep];
                int gc = (slot & 7) ^ (r & 7);
                GL16(vt + (size_t)(b * HD + r) * LL + k0 + gc * 8,
                     VTs + (size_t)slot * 8);
            }
            __syncthreads();

            // S = Q K^T
            floatx4 sacc[4];
#pragma unroll
            for (int nt = 0; nt < 4; ++nt)
                sacc[nt] = (floatx4){0.f, 0.f, 0.f, 0.f};
#pragma unroll
            for (int nt = 0; nt < 4; ++nt) {
#pragma unroll
                for (int kc = 0; kc < 4; ++kc) {
                    short8 bk = *reinterpret_cast<const short8*>(
                        &Ks[(nt * 16 + col) * 128 +
                            ((kc * 4 + quad) ^ sel) * 8]);
                    sacc[nt] = __builtin_amdgcn_mfma_f32_16x16x32_bf16(
                        aq[kc], bk, sacc[nt], 0, 0, 0);
                }
            }

            // p = exp2(s*scl2 - M2), causal-masked; accumulate per-lane l
            float psum[4] = {0.f, 0.f, 0.f, 0.f};
#pragma unroll
            for (int nt = 0; nt < 4; ++nt) {
                int kj = k0 + nt * 16 + col;
#pragma unroll
                for (int rr = 0; rr < 4; ++rr) {
                    int qi = q0 + w * 16 + quad * 4 + rr;
                    float p = exp2f(fmaf(sacc[nt][rr], scl2, -M2));
                    p = (kj <= qi) ? p : 0.0f;
                    sacc[nt][rr] = p;
                    psum[rr] += p;
                }
            }
#pragma unroll
            for (int rr = 0; rr < 4; ++rr) lrow[rr] += psum[rr];

            // P: C-layout -> LDS -> A-layout (per-wave buffer)
#pragma unroll
            for (int nt = 0; nt < 4; ++nt)
#pragma unroll
                for (int rr = 0; rr < 4; ++rr)
                    Ps[w][quad * 4 + rr][nt * 16 + col] = f2bf(sacc[nt][rr]);
            asm volatile("s_waitcnt lgkmcnt(0)" ::: "memory");

            // O += P V
#pragma unroll
            for (int kt2 = 0; kt2 < 2; ++kt2) {
                short8 ap = *reinterpret_cast<const short8*>(
                    &Ps[w][col][kt2 * 32 + quad * 8]);
#pragma unroll
                for (int dt = 0; dt < 8; ++dt) {
                    short8 bv = *reinterpret_cast<const short8*>(
                        &VTs[(dt * 16 + col) * 64 +
                             ((kt2 * 4 + quad) ^ sel) * 8]);
                    oacc[dt] = __builtin_amdgcn_mfma_f32_16x16x32_bf16(
                        ap, bv, oacc[dt], 0, 0, 0);
                }
            }
        }

        // epilogue: reduce per-lane l across the 16 row lanes, store bf16
#pragma unroll
        for (int off = 1; off < 16; off <<= 1)
#pragma unroll
            for (int rr = 0; rr < 4; ++rr)
                lrow[rr] += __shfl_xor(lrow[rr], off);
        float inv[4];
#pragma unroll
        for (int rr = 0; rr < 4; ++rr) inv[rr] = 1.0f / lrow[rr];
#pragma unroll
        for (int dt = 0; dt < 8; ++dt)
#pragma unroll
            for (int rr = 0; rr < 4; ++rr)
                aob[((size_t)(b * LL + q0 + w * 16 + quad * 4 + rr) * NH + h) *
                        HD + dt * 16 + col] = f2bf(oacc[dt][rr] * inv[rr]);
    }
}

// ---------------------------------------------------------------------------
extern "C" void kernel_launch(void* const* d_in, const int* in_sizes, int n_in,
                              void* d_out, int out_size, void* d_ws,
                              size_t ws_size, hipStream_t stream) {
    const float* x    = (const float*)d_in[0];
    const float* cosb = (const float*)d_in[1];
    const float* sinb = (const float*)d_in[2];
    const float* Wq   = (const float*)d_in[3];
    const float* Wk   = (const float*)d_in[4];
    const float* Wv   = (const float*)d_in[5];
    const float* Wo   = (const float*)d_in[6];
    float* out = (float*)d_out;

    float* qkv  = (float*)d_ws;                         // M*2304 f32
    ushort* xb  = (ushort*)(qkv + (size_t)MROWS * NKV); // M*DIM bf16
    ushort* qb  = xb + (size_t)MROWS * DIM;             // M*DIM bf16
    ushort* kb  = qb + (size_t)MROWS * DIM;             // M*HD bf16
    ushort* vt  = kb + (size_t)MROWS * HD;              // M*HD bf16 (B,D,L)
    ushort* aob = vt + (size_t)MROWS * HD;              // M*DIM bf16
    ushort* Wcatt = aob + (size_t)MROWS * DIM;          // 2304*2048 bf16
    ushort* Wot   = Wcatt + (size_t)NKV * DIM;          // 2048*2048 bf16

    conv_bf16<<<dim3(MROWS * DIM / (256 * 8)), 256, 0, stream>>>(x, xb);
    wprep<<<dim3(2176), 256, 0, stream>>>(Wq, Wk, Wv, Wo, Wcatt, Wot);

    // fused q|k|v projection: (M,2048) @ (2048,2304), 8-phase 256^2
    gemm8p<<<dim3(NKV / 256, MROWS / 256), 512, 0, stream>>>(xb, Wcatt, qkv,
                                                             NKV);

    // RoPE + RMSNorm -> bf16
    rope_rms_bf16<<<dim3(MROWS * NH / 4), 256, 0, stream>>>(
        qkv, qb, cosb, sinb, NH, MROWS * NH, NKV);
    rope_rms_bf16<<<dim3(MROWS / 4), 256, 0, stream>>>(
        qkv + DIM, kb, cosb, sinb, 1, MROWS, NKV);
    vtrans<<<dim3(LL / 64, 2, BB), 256, 0, stream>>>(qkv + DIM + HD, vt, NKV);

    // causal MQA attention
    flash_mfma<<<dim3(LL / 128, BB * NH), 256, 0, stream>>>(qb, kb, vt, aob);

    // output projection: (M,2048) @ (2048,2048), 8-phase 256^2
    gemm8p<<<dim3(DIM / 256, MROWS / 256), 512, 0, stream>>>(aob, Wot, out,
                                                             DIM);
}